// Round 2
// baseline (65.869 us; speedup 1.0000x reference)
//
#include <hip/hip_runtime.h>
#include <hip/hip_bf16.h>

#define NCLS 13

__global__ __launch_bounds__(256) void rnorm_kernel(
    const float* __restrict__ input,
    const int* __restrict__ target,
    const float* __restrict__ s,
    const float* __restrict__ C,
    float* __restrict__ out,
    int N)
{
    int n = blockIdx.x * blockDim.x + threadIdx.x;
    float res = 0.0f;
    if (n < N) {
        const float* x  = input + (size_t)n * NCLS;
        const float* sv = s     + (size_t)n * NCLS;
        const float* Cr = C     + (size_t)n * NCLS * NCLS;
        int t = target[n];

        float xr[NCLS];
#pragma unroll
        for (int j = 0; j < NCLS; ++j) xr[j] = x[j];

        float sp = 0.0f, sy = 0.0f, dd = 0.0f;
#pragma unroll
        for (int i = 0; i < NCLS; ++i) {
            float zye = 0.0f;
            float zpe = 0.0f;
#pragma unroll
            for (int j = 0; j < NCLS; ++j) {
                float c = Cr[i * NCLS + j];
                zye = fmaf(c, xr[j], zye);
                if (j == t) zpe = c;   // one-hot column extract, no extra load
            }
            float svi = sv[i];
            float zp = svi - zpe;
            float zy = svi - zye;
            sp = fmaf(zp, zp, sp);
            sy = fmaf(zy, zy, sy);
            dd = fmaf(zy, zp, dd);
        }
        // z_p_norm - diag / z_y_norm
        res = sqrtf(sp) - dd / sqrtf(sy);
    }

    // wave-64 reduction
#pragma unroll
    for (int off = 32; off > 0; off >>= 1)
        res += __shfl_down(res, off, 64);

    __shared__ float wsum[4];
    int lane = threadIdx.x & 63;
    int wid  = threadIdx.x >> 6;
    if (lane == 0) wsum[wid] = res;
    __syncthreads();
    if (threadIdx.x == 0) {
        float b = wsum[0] + wsum[1] + wsum[2] + wsum[3];
        atomicAdd(out, b);
    }
}

extern "C" void kernel_launch(void* const* d_in, const int* in_sizes, int n_in,
                              void* d_out, int out_size, void* d_ws, size_t ws_size,
                              hipStream_t stream) {
    const float* input  = (const float*)d_in[0];
    const int*   target = (const int*)d_in[1];   // harness passes integers as int32
    const float* s      = (const float*)d_in[2];
    const float* C      = (const float*)d_in[3];
    // d_in[4] (instance_weights) is unused by the reference.

    float* out = (float*)d_out;
    int N = in_sizes[1];  // target has N elements

    // harness poisons d_out and does not re-zero between replays
    hipMemsetAsync(out, 0, sizeof(float) * out_size, stream);

    int block = 256;
    int grid = (N + block - 1) / block;
    rnorm_kernel<<<grid, block, 0, stream>>>(input, target, s, C, out, N);
}

// Round 3
// 59.757 us; speedup vs baseline: 1.1023x; 1.1023x over previous
//
#include <hip/hip_runtime.h>
#include <hip/hip_bf16.h>

#define NCLS 13
#define ROWS_PER_TILE 64
#define BLOCK 256
#define TILES_PER_BLOCK 2

// C tile: 64 rows * 169 floats = 10816 floats = 2704 float4 = 43264 B
// x tile: 64 * 13 = 832 floats = 208 float4
// s tile: same

__global__ __launch_bounds__(BLOCK) void rnorm_kernel(
    const float* __restrict__ input,
    const int* __restrict__ target,
    const float* __restrict__ s,
    const float* __restrict__ C,
    float* __restrict__ out,
    int N)
{
    __shared__ float4 c_lds4[2704];
    __shared__ float4 x_lds4[208];
    __shared__ float4 s_lds4[208];
    __shared__ float  wsum[4];

    const float* c_lds = (const float*)c_lds4;
    const float* x_lds = (const float*)x_lds4;
    const float* s_lds = (const float*)s_lds4;

    const int tid = threadIdx.x;
    const int row_local = tid >> 2;   // 0..63, 4 threads per row
    const int q = tid & 3;

    const int ntiles = N / ROWS_PER_TILE;
    float res_acc = 0.0f;

    for (int tt = 0; tt < TILES_PER_BLOCK; ++tt) {
        const int tile = blockIdx.x * TILES_PER_BLOCK + tt;
        if (tile >= ntiles) break;
        const int base_row = tile * ROWS_PER_TILE;

        // ---- coalesced staging: global float4 -> LDS ----
        const float4* csrc = (const float4*)(C + (size_t)base_row * (NCLS * NCLS));
        for (int k = tid; k < 2704; k += BLOCK)
            c_lds4[k] = csrc[k];
        if (tid < 208) {
            const float4* xsrc = (const float4*)(input + (size_t)base_row * NCLS);
            const float4* ssrc = (const float4*)(s + (size_t)base_row * NCLS);
            x_lds4[tid] = xsrc[tid];
            s_lds4[tid] = ssrc[tid];
        }
        __syncthreads();

        const int t = target[base_row + row_local];

        // x row into registers (reused across this thread's i's)
        float xr[NCLS];
#pragma unroll
        for (int j = 0; j < NCLS; ++j) xr[j] = x_lds[row_local * NCLS + j];

        const float* crow = c_lds + row_local * (NCLS * NCLS);
        float sp = 0.0f, sy = 0.0f, dd = 0.0f;

        // i = q + 4*ii for ii=0..2 covers i=0..11; i=12 done by q==0
#pragma unroll
        for (int ii = 0; ii < 3; ++ii) {
            const int i = q + 4 * ii;
            float zye = 0.0f, zpe = 0.0f;
#pragma unroll
            for (int j = 0; j < NCLS; ++j) {
                const float c = crow[i * NCLS + j];
                zye = fmaf(c, xr[j], zye);
                if (j == t) zpe = c;
            }
            const float svi = s_lds[row_local * NCLS + i];
            const float zp = svi - zpe;
            const float zy = svi - zye;
            sp = fmaf(zp, zp, sp);
            sy = fmaf(zy, zy, sy);
            dd = fmaf(zy, zp, dd);
        }
        if (q == 0) {
            const int i = 12;
            float zye = 0.0f, zpe = 0.0f;
#pragma unroll
            for (int j = 0; j < NCLS; ++j) {
                const float c = crow[i * NCLS + j];
                zye = fmaf(c, xr[j], zye);
                if (j == t) zpe = c;
            }
            const float svi = s_lds[row_local * NCLS + i];
            const float zp = svi - zpe;
            const float zy = svi - zye;
            sp = fmaf(zp, zp, sp);
            sy = fmaf(zy, zy, sy);
            dd = fmaf(zy, zp, dd);
        }

        // combine the 4-lane group (lanes l, l^1, l^2 share a row)
        sp += __shfl_xor(sp, 1); sp += __shfl_xor(sp, 2);
        sy += __shfl_xor(sy, 1); sy += __shfl_xor(sy, 2);
        dd += __shfl_xor(dd, 1); dd += __shfl_xor(dd, 2);

        if (q == 0)
            res_acc += sqrtf(sp) - dd / sqrtf(sy);

        __syncthreads();  // LDS reused next tile
    }

    // ---- block reduction ----
#pragma unroll
    for (int off = 32; off > 0; off >>= 1)
        res_acc += __shfl_down(res_acc, off, 64);

    const int lane = tid & 63;
    const int wid  = tid >> 6;
    if (lane == 0) wsum[wid] = res_acc;
    __syncthreads();
    if (tid == 0) {
        atomicAdd(out, wsum[0] + wsum[1] + wsum[2] + wsum[3]);
    }
}

extern "C" void kernel_launch(void* const* d_in, const int* in_sizes, int n_in,
                              void* d_out, int out_size, void* d_ws, size_t ws_size,
                              hipStream_t stream) {
    const float* input  = (const float*)d_in[0];
    const int*   target = (const int*)d_in[1];   // harness passes integers as int32
    const float* s      = (const float*)d_in[2];
    const float* C      = (const float*)d_in[3];
    // d_in[4] (instance_weights) is unused by the reference.

    float* out = (float*)d_out;
    int N = in_sizes[1];  // target has N elements

    // harness poisons d_out and does not re-zero between replays
    hipMemsetAsync(out, 0, sizeof(float) * out_size, stream);

    const int ntiles = N / ROWS_PER_TILE;                       // 4096
    const int grid = (ntiles + TILES_PER_BLOCK - 1) / TILES_PER_BLOCK;  // 2048
    rnorm_kernel<<<grid, BLOCK, 0, stream>>>(input, target, s, C, out, N);
}

// Round 4
// 48.334 us; speedup vs baseline: 1.3628x; 1.2363x over previous
//
#include <hip/hip_runtime.h>
#include <hip/hip_bf16.h>

#define NCLS 13
#define ROWS 32                 // rows per tile
#define BLOCK 256               // 4 waves
#define TPB 8                   // tiles per block
#define C_FLOATS (ROWS * NCLS * NCLS)   // 5408 floats / tile
#define XS_FLOATS (ROWS * NCLS)         // 416 floats / tile
#define C_F4 (C_FLOATS / 4)             // 1352
#define XS_F4 (XS_FLOATS / 4)           // 104

// async global->LDS, 16B per lane; dest must be wave-uniform base + lane*16
__device__ __forceinline__ void async_cp16(const float* g, float* l) {
    __builtin_amdgcn_global_load_lds(
        (__attribute__((address_space(1))) void*)(const_cast<float*>(g)),
        (__attribute__((address_space(3))) void*)(l),
        16, 0, 0);
}

__device__ __forceinline__ void stage_tile(float* cb, float* xb, float* sb,
                                           const float* Cg, const float* xg,
                                           const float* sg, int tid) {
#pragma unroll
    for (int m = 0; m < 6; ++m) {
        int k = m * BLOCK + tid;
        if (k < C_F4)
            async_cp16(Cg + (size_t)k * 4, cb + (size_t)k * 4);
    }
    if (tid < XS_F4)
        async_cp16(xg + (size_t)tid * 4, xb + (size_t)tid * 4);
    else if (tid >= 128 && tid < 128 + XS_F4)
        async_cp16(sg + (size_t)(tid - 128) * 4, sb + (size_t)(tid - 128) * 4);
}

__global__ __launch_bounds__(BLOCK) void rnorm_kernel(
    const float* __restrict__ input,
    const int* __restrict__ target,
    const float* __restrict__ s,
    const float* __restrict__ C,
    float* __restrict__ out,
    int ntiles)
{
    __shared__ __align__(16) float cbuf[2][C_FLOATS];
    __shared__ __align__(16) float xbuf[2][XS_FLOATS];
    __shared__ __align__(16) float sbuf[2][XS_FLOATS];
    __shared__ float wsum[4];

    const int tid = threadIdx.x;
    const int row = tid >> 3;   // 0..31
    const int q   = tid & 7;    // 8 threads per row

    const int tile0 = blockIdx.x * TPB;
    const int nt = min(TPB, ntiles - tile0);
    float res_acc = 0.0f;

    if (nt > 0) {
        // prologue: stage tile 0
        stage_tile(cbuf[0], xbuf[0], sbuf[0],
                   C + (size_t)tile0 * C_FLOATS,
                   input + (size_t)tile0 * XS_FLOATS,
                   s + (size_t)tile0 * XS_FLOATS, tid);
        int t_cur = target[tile0 * ROWS + row];
        asm volatile("s_waitcnt vmcnt(0)" ::: "memory");
        __syncthreads();

        for (int t = 0; t < nt; ++t) {
            const int cur = t & 1;
            const float* cb = cbuf[cur];
            const float* xb = xbuf[cur];
            const float* sb = sbuf[cur];

            int t_next = 0;
            if (t + 1 < nt) {
                const int tile = tile0 + t + 1;
                stage_tile(cbuf[cur ^ 1], xbuf[cur ^ 1], sbuf[cur ^ 1],
                           C + (size_t)tile * C_FLOATS,
                           input + (size_t)tile * XS_FLOATS,
                           s + (size_t)tile * XS_FLOATS, tid);
                t_next = target[tile * ROWS + row];
            }

            // ---- compute tile t from LDS ----
            float xr[NCLS];
#pragma unroll
            for (int j = 0; j < NCLS; ++j) xr[j] = xb[row * NCLS + j];

            const float* crow = cb + row * (NCLS * NCLS);
            float sp = 0.0f, sy = 0.0f, dd = 0.0f;
            const int tt = t_cur;

            {   // i = q  (covers i = 0..7 across the 8-thread group)
                const int i = q;
                float zye = 0.0f, zpe = 0.0f;
#pragma unroll
                for (int j = 0; j < NCLS; ++j) {
                    const float c = crow[i * NCLS + j];
                    zye = fmaf(c, xr[j], zye);
                    if (j == tt) zpe = c;
                }
                const float svi = sb[row * NCLS + i];
                const float zp = svi - zpe, zy = svi - zye;
                sp = fmaf(zp, zp, sp); sy = fmaf(zy, zy, sy); dd = fmaf(zy, zp, dd);
            }
            if (q < 5) {   // i = q + 8 (covers i = 8..12)
                const int i = q + 8;
                float zye = 0.0f, zpe = 0.0f;
#pragma unroll
                for (int j = 0; j < NCLS; ++j) {
                    const float c = crow[i * NCLS + j];
                    zye = fmaf(c, xr[j], zye);
                    if (j == tt) zpe = c;
                }
                const float svi = sb[row * NCLS + i];
                const float zp = svi - zpe, zy = svi - zye;
                sp = fmaf(zp, zp, sp); sy = fmaf(zy, zy, sy); dd = fmaf(zy, zp, dd);
            }

            // reduce across the 8-lane row group
            sp += __shfl_xor(sp, 1); sp += __shfl_xor(sp, 2); sp += __shfl_xor(sp, 4);
            sy += __shfl_xor(sy, 1); sy += __shfl_xor(sy, 2); sy += __shfl_xor(sy, 4);
            dd += __shfl_xor(dd, 1); dd += __shfl_xor(dd, 2); dd += __shfl_xor(dd, 4);

            if (q == 0)
                res_acc += sqrtf(sp) - dd / sqrtf(sy);

            if (t + 1 < nt) {
                // drain this wave's async loads for tile t+1, then barrier
                asm volatile("s_waitcnt vmcnt(0)" ::: "memory");
                __syncthreads();
                t_cur = t_next;
            }
        }
    }

    // ---- block reduction ----
#pragma unroll
    for (int off = 32; off > 0; off >>= 1)
        res_acc += __shfl_down(res_acc, off, 64);

    const int lane = tid & 63;
    const int wid  = tid >> 6;
    if (lane == 0) wsum[wid] = res_acc;
    __syncthreads();
    if (tid == 0)
        atomicAdd(out, wsum[0] + wsum[1] + wsum[2] + wsum[3]);
}

extern "C" void kernel_launch(void* const* d_in, const int* in_sizes, int n_in,
                              void* d_out, int out_size, void* d_ws, size_t ws_size,
                              hipStream_t stream) {
    const float* input  = (const float*)d_in[0];
    const int*   target = (const int*)d_in[1];   // harness passes integers as int32
    const float* s      = (const float*)d_in[2];
    const float* C      = (const float*)d_in[3];
    // d_in[4] (instance_weights) is unused by the reference.

    float* out = (float*)d_out;
    int N = in_sizes[1];

    // harness poisons d_out and does not re-zero between replays
    hipMemsetAsync(out, 0, sizeof(float) * out_size, stream);

    const int ntiles = N / ROWS;                        // 8192
    const int grid = (ntiles + TPB - 1) / TPB;          // 1024
    rnorm_kernel<<<grid, BLOCK, 0, stream>>>(input, target, s, C, out, ntiles);
}